// Round 3
// baseline (352.996 us; speedup 1.0000x reference)
//
#include <hip/hip_runtime.h>
#include <hip/hip_bf16.h>
#include <stdint.h>

// LSTM cell fused kernel for MI355X (gfx950).
// gates = [X | h_prev] @ [W_ih | W_hh]^T  (one GEMM, M=8192, N=4096, K=2048)
// Round 3: 256x256 tile, 8 waves (2Mx4N), BK=64, 8-phase-per-2-K-tiles
// schedule with counted vmcnt (T3+T4) + setprio (T5). Staging half-tiles are
// K-split (256 rows x 32 k = 16 KB, row stride 64 B) so ds_read_b128 fragment
// reads are contiguous 1024 B => bank-conflict-free with LINEAR LDS (no
// swizzle needed, global_load_lds-compatible). LSTM epilogue fused in-kernel.

typedef __attribute__((ext_vector_type(8))) __bf16 bf16x8;
typedef __attribute__((ext_vector_type(8))) unsigned short u16x8;
typedef __attribute__((ext_vector_type(4))) float f32x4;

__device__ __forceinline__ unsigned short f2bf(float f) {
  union { float f; unsigned int u; } v; v.f = f;
  unsigned int r = v.u + 0x7FFFu + ((v.u >> 16) & 1u);  // RNE
  return (unsigned short)(r >> 16);
}

// Linear f32 -> bf16 conversion of all four operand tensors, one dispatch.
__global__ void cvt_all(const float* __restrict__ s0, const float* __restrict__ s1,
                        const float* __restrict__ s2, const float* __restrict__ s3,
                        unsigned short* __restrict__ d0, unsigned short* __restrict__ d1,
                        unsigned short* __restrict__ d2, unsigned short* __restrict__ d3) {
  const float* src; unsigned short* dst; int n8;
  if (blockIdx.y == 0)      { src = s0; dst = d0; n8 = 8192 * 128; }
  else if (blockIdx.y == 1) { src = s1; dst = d1; n8 = 8192 * 128; }
  else if (blockIdx.y == 2) { src = s2; dst = d2; n8 = 4096 * 128; }
  else                      { src = s3; dst = d3; n8 = 4096 * 128; }
  int i = blockIdx.x * blockDim.x + threadIdx.x;
  int stride = gridDim.x * blockDim.x;
  for (; i < n8; i += stride) {
    float4 a = ((const float4*)src)[2 * i];
    float4 b = ((const float4*)src)[2 * i + 1];
    u16x8 o;
    o[0] = f2bf(a.x); o[1] = f2bf(a.y); o[2] = f2bf(a.z); o[3] = f2bf(a.w);
    o[4] = f2bf(b.x); o[5] = f2bf(b.y); o[6] = f2bf(b.z); o[7] = f2bf(b.w);
    *(u16x8*)&dst[(size_t)i * 8] = o;
  }
}

// Half-tile stream: H(g), g = 4*t + j; j: 0=A_k0, 1=B_k0, 2=A_k1, 3=B_k1.
// Slot = g mod 8 (8 x 16 KB). Stage H(4t+6+p) at phase p of tile t.
// Tile-end wait: vmcnt(4) (= 2 half-tiles / 4 loads outstanding), vmcnt(0)
// at t==30 (last prefetch drains).
#define STAGE_HALF(G) do {                                                     \
    const int t_ = (G) >> 2, j_ = (G) & 3;                                     \
    const int hks_ = j_ >> 1, isB_ = j_ & 1;                                   \
    const unsigned short* bA_; const unsigned short* bB_; int kk_;             \
    if (t_ < 16) { bA_ = Xb; bB_ = Wihb; kk_ = t_ * 64; }                      \
    else         { bA_ = Hb; bB_ = Whhb; kk_ = (t_ - 16) * 64; }               \
    const int col_ = kk_ + hks_ * 32 + scol;                                   \
    char* lb_ = smem + (((G) & 7) * 16384);                                    \
    _Pragma("unroll")                                                          \
    for (int r_ = 0; r_ < 2; ++r_) {                                           \
      const int row_ = r_ * 128 + srow;                                        \
      const unsigned short* src_ = isB_                                        \
          ? bB_ + (size_t)((row_ >> 6) * 1024 + h0 + (row_ & 63)) * 1024 + col_\
          : bA_ + (size_t)(m0 + row_) * 1024 + col_;                           \
      __builtin_amdgcn_global_load_lds(                                        \
          (const __attribute__((address_space(1))) void*)src_,                 \
          (__attribute__((address_space(3))) void*)(lb_ + r_ * 8192 + tid * 16),\
          16, 0, 0);                                                           \
    }                                                                          \
  } while (0)

// Phase P of tile T (buffer parity B): quadrant = (m-half = P&1, ks = P>>1).
// 8 x ds_read_b128 (contiguous, conflict-free), 1 half-tile stage, barrier,
// 16 MFMA under setprio(1), barrier.
#define PHASE(T, B, P) do {                                                    \
    const int ks_ = (P) >> 1, mh_ = (P) & 1;                                   \
    const char* sa_ = smem + (4 * (B) + 2 * ks_) * 16384;                      \
    const char* sb_ = smem + (4 * (B) + 2 * ks_ + 1) * 16384;                  \
    bf16x8 af_[4], bf_[4];                                                     \
    _Pragma("unroll")                                                          \
    for (int m2 = 0; m2 < 4; ++m2) {                                           \
      u16x8 t8 = *(const u16x8*)(sa_ +                                         \
          ((wr * 128 + (mh_ * 4 + m2) * 16 + l15) * 64 + l4 * 16));            \
      af_[m2] = __builtin_bit_cast(bf16x8, t8);                                \
    }                                                                          \
    _Pragma("unroll")                                                          \
    for (int n_ = 0; n_ < 4; ++n_) {                                           \
      u16x8 t8 = *(const u16x8*)(sb_ +                                         \
          ((wc * 64 + n_ * 16 + l15) * 64 + l4 * 16));                         \
      bf_[n_] = __builtin_bit_cast(bf16x8, t8);                                \
    }                                                                          \
    if (4 * (T) + 6 + (P) < 128) { STAGE_HALF(4 * (T) + 6 + (P)); }            \
    __builtin_amdgcn_s_barrier();                                              \
    __builtin_amdgcn_s_setprio(1);                                             \
    _Pragma("unroll")                                                          \
    for (int m2 = 0; m2 < 4; ++m2)                                             \
      _Pragma("unroll")                                                        \
      for (int n_ = 0; n_ < 4; ++n_)                                           \
        acc[mh_ * 4 + m2][n_] = __builtin_amdgcn_mfma_f32_16x16x32_bf16(       \
            af_[m2], bf_[n_], acc[mh_ * 4 + m2][n_], 0, 0, 0);                 \
    __builtin_amdgcn_s_setprio(0);                                             \
    __builtin_amdgcn_s_barrier();                                              \
  } while (0)

#define TILE(T, B) do {                                                        \
    PHASE(T, B, 0); PHASE(T, B, 1); PHASE(T, B, 2); PHASE(T, B, 3);            \
    if ((T) < 31) {                                                            \
      if ((T) == 30) { asm volatile("s_waitcnt vmcnt(0)" ::: "memory"); }      \
      else           { asm volatile("s_waitcnt vmcnt(4)" ::: "memory"); }      \
      __builtin_amdgcn_s_barrier();                                            \
    }                                                                          \
  } while (0)

__global__ __launch_bounds__(512, 2) void lstm_fused(
    const unsigned short* __restrict__ Xb, const unsigned short* __restrict__ Hb,
    const unsigned short* __restrict__ Wihb, const unsigned short* __restrict__ Whhb,
    const float* __restrict__ bih, const float* __restrict__ bhh,
    const float* __restrict__ cprev, float* __restrict__ out) {
  __shared__ __align__(16) char smem[131072];  // 8 staging slots, reused by epilogue

  const int tid = threadIdx.x;
  const int lane = tid & 63;
  const int wid = tid >> 6;
  const int wr = wid >> 2;   // 0..1 : wave row (128 rows)
  const int wc = wid & 3;    // 0..3 : wave col (64 cols = one gate)
  const int l15 = lane & 15;
  const int l4 = lane >> 4;

  // bijective XCD-chunked swizzle (512 % 8 == 0): XCD k -> 4 consecutive
  // m-tiles x all 16 n-tiles (A-panel L2 reuse).
  const int bid = blockIdx.x;
  const int tile_id = (bid & 7) * 64 + (bid >> 3);
  const int m0 = (tile_id >> 4) * 256;  // batch-row tile
  const int h0 = (tile_id & 15) * 64;   // hidden-unit tile (x 4 gates = 256 cols)

  // staging: thread -> row tid>>2 (128 rows/round), 16B chunk tid&3 of 64B row
  const int srow = tid >> 2;
  const int scol = (tid & 3) * 8;

  f32x4 acc[8][4];
#pragma unroll
  for (int m = 0; m < 8; ++m)
#pragma unroll
    for (int n = 0; n < 4; ++n) {
      f32x4 z = {0.f, 0.f, 0.f, 0.f};
      acc[m][n] = z;
    }

  // Prologue: stage H0..H5, require H0..H3 landed (vmcnt(4) = 2 halves out).
  STAGE_HALF(0); STAGE_HALF(1); STAGE_HALF(2);
  STAGE_HALF(3); STAGE_HALF(4); STAGE_HALF(5);
  asm volatile("s_waitcnt vmcnt(4)" ::: "memory");
  __builtin_amdgcn_s_barrier();

#pragma unroll 1
  for (int th = 0; th < 16; ++th) {
    const int t0 = th * 2;
    TILE(t0, 0);
    TILE(t0 + 1, 1);
  }

  // ---- fused LSTM epilogue: exchange acc via LDS, 2 row-phases of 128 ----
  // layout: [gate(wc)][m(0..7)][n(0..3)][lane][4 regs] f32 -> f32x4 per lane,
  // contiguous 1024 B per (wc,m,n) store/load group => conflict-free.
  __syncthreads();
#pragma unroll
  for (int ph = 0; ph < 2; ++ph) {
    if (ph) __syncthreads();
    if (wr == ph) {
#pragma unroll
      for (int m = 0; m < 8; ++m)
#pragma unroll
        for (int n = 0; n < 4; ++n)
          *(f32x4*)(smem + (((wc * 8 + m) * 4 + n) * 64 + lane) * 16) = acc[m][n];
    }
    __syncthreads();
#pragma unroll
    for (int q = 0; q < 4; ++q) {
      f32x4 vg[4];
#pragma unroll
      for (int g = 0; g < 4; ++g)
        vg[g] = *(const f32x4*)(smem + (((g * 8 + wid) * 4 + q) * 64 + lane) * 16);
      const int gcol = h0 + q * 16 + l15;
      const float b0 = bih[gcol]        + bhh[gcol];
      const float b1 = bih[1024 + gcol] + bhh[1024 + gcol];
      const float b2 = bih[2048 + gcol] + bhh[2048 + gcol];
      const float b3 = bih[3072 + gcol] + bhh[3072 + gcol];
#pragma unroll
      for (int j = 0; j < 4; ++j) {
        const size_t row = (size_t)(m0 + ph * 128 + wid * 16 + l4 * 4 + j);
        const float vi = vg[0][j] + b0;
        const float vf = vg[1][j] + b1;
        const float vgt = vg[2][j] + b2;
        const float vo = vg[3][j] + b3;
        const float si = 1.f / (1.f + __expf(-vi));
        const float sf = 1.f / (1.f + __expf(-vf));
        const float tg = tanhf(vgt);
        const float so = 1.f / (1.f + __expf(-vo));
        const float cp = cprev[row * 1024 + gcol];
        const float ct = sf * cp + si * tg;
        const float ht = so * tanhf(ct);
        out[row * 1024 + gcol] = ht;                 // h_t
        out[8388608 + row * 1024 + gcol] = ct;       // c_t
      }
    }
  }
}

extern "C" void kernel_launch(void* const* d_in, const int* in_sizes, int n_in,
                              void* d_out, int out_size, void* d_ws, size_t ws_size,
                              hipStream_t stream) {
  const float* input  = (const float*)d_in[0];
  const float* h_prev = (const float*)d_in[1];
  const float* c_prev = (const float*)d_in[2];
  const float* W_ih   = (const float*)d_in[3];
  const float* b_ih   = (const float*)d_in[4];
  const float* W_hh   = (const float*)d_in[5];
  const float* b_hh   = (const float*)d_in[6];
  float* out = (float*)d_out;

  unsigned short* Xb   = (unsigned short*)d_ws;
  unsigned short* Hb   = Xb + (size_t)8192 * 1024;
  unsigned short* Wihb = Hb + (size_t)8192 * 1024;
  unsigned short* Whhb = Wihb + (size_t)4096 * 1024;
  // ws use: (8192+8192+4096+4096)*1024*2 = 50,331,648 bytes

  dim3 cgrid(1024, 4);
  cvt_all<<<cgrid, 256, 0, stream>>>(input, h_prev, W_ih, W_hh, Xb, Hb, Wihb, Whhb);

  lstm_fused<<<512, 512, 0, stream>>>(Xb, Hb, Wihb, Whhb, b_ih, b_hh, c_prev, out);
}

// Round 4
// 339.029 us; speedup vs baseline: 1.0412x; 1.0412x over previous
//
#include <hip/hip_runtime.h>
#include <hip/hip_bf16.h>
#include <stdint.h>

// LSTM cell fused kernel for MI355X (gfx950).
// gates = [X | h_prev] @ [W_ih | W_hh]^T  (one GEMM, M=8192, N=4096, K=2048)
// Round 4: same 256x256 8-phase counted-vmcnt schedule as R3, but the
// half-tile in-row chunk placement is XOR-swizzled (chunk c of each 32-elem
// K-group stored at c ^ ((row>>1)&3), pre-applied in ws by cvt_swz4) so the
// ds_read_b128 fragment reads spread over all 8 bank clusters (2-way = free)
// instead of R3's 8-way conflict.

typedef __attribute__((ext_vector_type(8))) __bf16 bf16x8;
typedef __attribute__((ext_vector_type(8))) unsigned short u16x8;
typedef __attribute__((ext_vector_type(4))) float f32x4;

__device__ __forceinline__ unsigned short f2bf(float f) {
  union { float f; unsigned int u; } v; v.f = f;
  unsigned int r = v.u + 0x7FFFu + ((v.u >> 16) & 1u);  // RNE
  return (unsigned short)(r >> 16);
}

// f32 -> bf16 of all four operands, one dispatch. Output chunk (16 B = 8
// elems) c within each 4-chunk (32-elem) K-group stored at c ^ ((row>>1)&3).
__global__ void cvt_swz4(const float* __restrict__ s0, const float* __restrict__ s1,
                         const float* __restrict__ s2, const float* __restrict__ s3,
                         unsigned short* __restrict__ d0, unsigned short* __restrict__ d1,
                         unsigned short* __restrict__ d2, unsigned short* __restrict__ d3) {
  const float* src; unsigned short* dst; int n8;
  if (blockIdx.y == 0)      { src = s0; dst = d0; n8 = 8192 * 128; }
  else if (blockIdx.y == 1) { src = s1; dst = d1; n8 = 8192 * 128; }
  else if (blockIdx.y == 2) { src = s2; dst = d2; n8 = 4096 * 128; }
  else                      { src = s3; dst = d3; n8 = 4096 * 128; }
  int i = blockIdx.x * blockDim.x + threadIdx.x;
  int stride = gridDim.x * blockDim.x;
  for (; i < n8; i += stride) {
    int row = i >> 7;
    int cw = i & 127;       // chunk within row
    int grp = cw >> 2;      // 32-elem K-group
    int c = cw & 3;         // chunk within group
    float4 a = ((const float4*)src)[2 * i];
    float4 b = ((const float4*)src)[2 * i + 1];
    u16x8 o;
    o[0] = f2bf(a.x); o[1] = f2bf(a.y); o[2] = f2bf(a.z); o[3] = f2bf(a.w);
    o[4] = f2bf(b.x); o[5] = f2bf(b.y); o[6] = f2bf(b.z); o[7] = f2bf(b.w);
    int oc = (row << 7) + (grp << 2) + (c ^ ((row >> 1) & 3));
    *(u16x8*)&dst[(size_t)oc * 8] = o;
  }
}

// Half-tile stream: H(g), g = 4*t + j; j: 0=A_k0, 1=B_k0, 2=A_k1, 3=B_k1.
// Each half = 256 rows x 32 k = 16 KB, slot = g mod 8. Stage H(4t+6+p) at
// phase p of tile t. Tile-end wait: vmcnt(4); vmcnt(0) only at t==30.
#define STAGE_HALF(G) do {                                                     \
    const int t_ = (G) >> 2, j_ = (G) & 3;                                     \
    const int hks_ = j_ >> 1, isB_ = j_ & 1;                                   \
    const unsigned short* bA_; const unsigned short* bB_; int kk_;             \
    if (t_ < 16) { bA_ = Xb; bB_ = Wihb; kk_ = t_ * 64; }                      \
    else         { bA_ = Hb; bB_ = Whhb; kk_ = (t_ - 16) * 64; }               \
    const int col_ = kk_ + hks_ * 32 + scol;                                   \
    char* lb_ = smem + (((G) & 7) * 16384);                                    \
    _Pragma("unroll")                                                          \
    for (int r_ = 0; r_ < 2; ++r_) {                                           \
      const int row_ = r_ * 128 + srow;                                        \
      const unsigned short* src_ = isB_                                        \
          ? bB_ + (size_t)((row_ >> 6) * 1024 + h0 + (row_ & 63)) * 1024 + col_\
          : bA_ + (size_t)(m0 + row_) * 1024 + col_;                           \
      __builtin_amdgcn_global_load_lds(                                        \
          (const __attribute__((address_space(1))) void*)src_,                 \
          (__attribute__((address_space(3))) void*)(lb_ + r_ * 8192 + tid * 16),\
          16, 0, 0);                                                           \
    }                                                                          \
  } while (0)

// Phase P of tile T (buffer parity B): quadrant (ks = P>>1, m-half = P&1).
// 8 x ds_read_b128 (XOR-swizzled chunk, 2-way max), 1 half-tile stage,
// barrier, 16 MFMA under setprio(1), barrier.
#define PHASE(T, B, P) do {                                                    \
    const int ks_ = (P) >> 1, mh_ = (P) & 1;                                   \
    const char* sa_ = smem + (4 * (B) + 2 * ks_) * 16384;                      \
    const char* sb_ = smem + (4 * (B) + 2 * ks_ + 1) * 16384;                  \
    bf16x8 af_[4], bf_[4];                                                     \
    _Pragma("unroll")                                                          \
    for (int m2 = 0; m2 < 4; ++m2) {                                           \
      const int ra_ = wr * 128 + (mh_ * 4 + m2) * 16 + l15;                    \
      u16x8 t8 = *(const u16x8*)(sa_ + ra_ * 64 + xc_);                        \
      af_[m2] = __builtin_bit_cast(bf16x8, t8);                                \
    }                                                                          \
    _Pragma("unroll")                                                          \
    for (int n_ = 0; n_ < 4; ++n_) {                                           \
      const int rb_ = wc * 64 + n_ * 16 + l15;                                 \
      u16x8 t8 = *(const u16x8*)(sb_ + rb_ * 64 + xc_);                        \
      bf_[n_] = __builtin_bit_cast(bf16x8, t8);                                \
    }                                                                          \
    if (4 * (T) + 6 + (P) < 128) { STAGE_HALF(4 * (T) + 6 + (P)); }            \
    __builtin_amdgcn_s_barrier();                                              \
    __builtin_amdgcn_s_setprio(1);                                             \
    _Pragma("unroll")                                                          \
    for (int m2 = 0; m2 < 4; ++m2)                                             \
      _Pragma("unroll")                                                        \
      for (int n_ = 0; n_ < 4; ++n_)                                           \
        acc[mh_ * 4 + m2][n_] = __builtin_amdgcn_mfma_f32_16x16x32_bf16(       \
            af_[m2], bf_[n_], acc[mh_ * 4 + m2][n_], 0, 0, 0);                 \
    __builtin_amdgcn_s_setprio(0);                                             \
    __builtin_amdgcn_s_barrier();                                              \
  } while (0)

#define TILE(T, B) do {                                                        \
    PHASE(T, B, 0); PHASE(T, B, 1); PHASE(T, B, 2); PHASE(T, B, 3);            \
    if ((T) < 31) {                                                            \
      if ((T) == 30) { asm volatile("s_waitcnt vmcnt(0)" ::: "memory"); }      \
      else           { asm volatile("s_waitcnt vmcnt(4)" ::: "memory"); }      \
      __builtin_amdgcn_s_barrier();                                            \
    }                                                                          \
  } while (0)

__global__ __launch_bounds__(512, 2) void lstm_fused(
    const unsigned short* __restrict__ Xb, const unsigned short* __restrict__ Hb,
    const unsigned short* __restrict__ Wihb, const unsigned short* __restrict__ Whhb,
    const float* __restrict__ bih, const float* __restrict__ bhh,
    const float* __restrict__ cprev, float* __restrict__ out) {
  __shared__ __align__(16) char smem[131072];  // 8 staging slots, reused by epilogue

  const int tid = threadIdx.x;
  const int lane = tid & 63;
  const int wid = tid >> 6;
  const int wr = wid >> 2;   // 0..1 : wave row (128 rows)
  const int wc = wid & 3;    // 0..3 : wave col (64 cols = one gate)
  const int l15 = lane & 15;
  const int l4 = lane >> 4;
  // swizzled chunk byte offset within a 64 B row: (l4 ^ ((row>>1)&3)) * 16,
  // and row bits 1:2 == l15 bits 1:2 for every fragment row we read.
  const int xc_ = (l4 ^ ((l15 >> 1) & 3)) * 16;

  // bijective XCD-chunked swizzle (512 % 8 == 0)
  const int bid = blockIdx.x;
  const int tile_id = (bid & 7) * 64 + (bid >> 3);
  const int m0 = (tile_id >> 4) * 256;  // batch-row tile
  const int h0 = (tile_id & 15) * 64;   // hidden-unit tile (x 4 gates)

  // staging: thread -> row tid>>2 (128 rows/issue), 16B chunk tid&3
  const int srow = tid >> 2;
  const int scol = (tid & 3) * 8;

  f32x4 acc[8][4];
#pragma unroll
  for (int m = 0; m < 8; ++m)
#pragma unroll
    for (int n = 0; n < 4; ++n) {
      f32x4 z = {0.f, 0.f, 0.f, 0.f};
      acc[m][n] = z;
    }

  // Prologue: stage H0..H5, require H0..H3 landed (vmcnt(4) = 2 halves out).
  STAGE_HALF(0); STAGE_HALF(1); STAGE_HALF(2);
  STAGE_HALF(3); STAGE_HALF(4); STAGE_HALF(5);
  asm volatile("s_waitcnt vmcnt(4)" ::: "memory");
  __builtin_amdgcn_s_barrier();

#pragma unroll 1
  for (int th = 0; th < 16; ++th) {
    const int t0 = th * 2;
    TILE(t0, 0);
    TILE(t0 + 1, 1);
  }

  // ---- fused LSTM epilogue: exchange acc via LDS, 2 row-phases of 128 ----
  __syncthreads();
#pragma unroll
  for (int ph = 0; ph < 2; ++ph) {
    if (ph) __syncthreads();
    if (wr == ph) {
#pragma unroll
      for (int m = 0; m < 8; ++m)
#pragma unroll
        for (int n = 0; n < 4; ++n)
          *(f32x4*)(smem + (((wc * 8 + m) * 4 + n) * 64 + lane) * 16) = acc[m][n];
    }
    __syncthreads();
#pragma unroll
    for (int q = 0; q < 4; ++q) {
      f32x4 vg[4];
#pragma unroll
      for (int g = 0; g < 4; ++g)
        vg[g] = *(const f32x4*)(smem + (((g * 8 + wid) * 4 + q) * 64 + lane) * 16);
      const int gcol = h0 + q * 16 + l15;
      const float b0 = bih[gcol]        + bhh[gcol];
      const float b1 = bih[1024 + gcol] + bhh[1024 + gcol];
      const float b2 = bih[2048 + gcol] + bhh[2048 + gcol];
      const float b3 = bih[3072 + gcol] + bhh[3072 + gcol];
#pragma unroll
      for (int j = 0; j < 4; ++j) {
        const size_t row = (size_t)(m0 + ph * 128 + wid * 16 + l4 * 4 + j);
        const float vi = vg[0][j] + b0;
        const float vf = vg[1][j] + b1;
        const float vgt = vg[2][j] + b2;
        const float vo = vg[3][j] + b3;
        const float si = 1.f / (1.f + __expf(-vi));
        const float sf = 1.f / (1.f + __expf(-vf));
        const float tg = tanhf(vgt);
        const float so = 1.f / (1.f + __expf(-vo));
        const float cp = cprev[row * 1024 + gcol];
        const float ct = sf * cp + si * tg;
        const float ht = so * tanhf(ct);
        out[row * 1024 + gcol] = ht;                 // h_t
        out[8388608 + row * 1024 + gcol] = ct;       // c_t
      }
    }
  }
}

extern "C" void kernel_launch(void* const* d_in, const int* in_sizes, int n_in,
                              void* d_out, int out_size, void* d_ws, size_t ws_size,
                              hipStream_t stream) {
  const float* input  = (const float*)d_in[0];
  const float* h_prev = (const float*)d_in[1];
  const float* c_prev = (const float*)d_in[2];
  const float* W_ih   = (const float*)d_in[3];
  const float* b_ih   = (const float*)d_in[4];
  const float* W_hh   = (const float*)d_in[5];
  const float* b_hh   = (const float*)d_in[6];
  float* out = (float*)d_out;

  unsigned short* Xb   = (unsigned short*)d_ws;
  unsigned short* Hb   = Xb + (size_t)8192 * 1024;
  unsigned short* Wihb = Hb + (size_t)8192 * 1024;
  unsigned short* Whhb = Wihb + (size_t)4096 * 1024;
  // ws use: (8192+8192+4096+4096)*1024*2 = 50,331,648 bytes

  dim3 cgrid(1024, 4);
  cvt_swz4<<<cgrid, 256, 0, stream>>>(input, h_prev, W_ih, W_hh, Xb, Hb, Wihb, Whhb);

  lstm_fused<<<512, 512, 0, stream>>>(Xb, Hb, Wihb, Whhb, b_ih, b_hh, c_prev, out);
}